// Round 10
// baseline (394.194 us; speedup 1.0000x reference)
//
#include <hip/hip_runtime.h>
#include <hip/hip_fp16.h>

#define N_NODES 50000
#define N_EDGES 800000
#define N_GRAPHS 256
#define F_IN 112
#define DIM 32
#define BN_EPS 1e-5
#define PAD 32     // ints per atomic slot: one 128-B line per cursor
#define CAP 64     // edge slots per node (P(deg>63) ~ 1e-19 for Poisson(16))
#define NB 1563    // buckets = ceil(50000/32)
#define NREP 8     // one bucket replica per XCD
#define RCAP 128   // entries per replica-bucket (Poisson(64), 8 sigma headroom)
#define NSLICE 4   // feature slices of 32 for L2-resident layer-1 gather

typedef __attribute__((ext_vector_type(8))) short short8;
typedef __attribute__((ext_vector_type(4))) float float4v;

// ---- bf16 helpers (RNE) ----
__device__ inline unsigned short f2bf(float f) {
    union { float f; unsigned int u; } v; v.f = f;
    unsigned int u = v.u;
    u += 0x7FFFu + ((u >> 16) & 1u);
    return (unsigned short)(u >> 16);
}
__device__ inline float bf2f(unsigned short h) {
    union { unsigned int u; float f; } v; v.u = ((unsigned int)h) << 16;
    return v.f;
}

__device__ inline void w_split_body(const float* __restrict__ W, int K, int N, int Kpad,
                                    unsigned short* __restrict__ hi_t,
                                    unsigned short* __restrict__ lo_t, int idx) {
    if (idx >= N * Kpad) return;
    int n = idx / Kpad, k = idx - n * Kpad;
    float v = (k < K) ? W[(size_t)k * N + n] : 0.f;
    unsigned short h = f2bf(v);
    hi_t[idx] = h;
    lo_t[idx] = f2bf(v - bf2f(h));
}

// ------- merged prep: x -> slice-major fp16, 3 weight splits, graph bounds
#define PB_XH 12500                 // 50000*64 half2 / 256
#define PB_W1 (PB_XH + 56)
#define PB_W2 (PB_W1 + 56)
#define PB_W4 (PB_W2 + 4)
#define PB_GB (PB_W4 + 196)        // total blocks
__global__ __launch_bounds__(256) void prep_kernel(const float* __restrict__ X, __half* __restrict__ Xs,
                                                   const float* __restrict__ g1_w1, unsigned short* w1h, unsigned short* w1l,
                                                   const float* __restrict__ g1_w2, unsigned short* w2h, unsigned short* w2l,
                                                   const float* __restrict__ g2_w2, unsigned short* w4h, unsigned short* w4l,
                                                   const int* __restrict__ batch, int* __restrict__ goff) {
    int b = blockIdx.x, t = threadIdx.x;
    if (b < PB_XH) {
        int idx = b * 256 + t;                       // half2 index over node x 64
        if (idx >= N_NODES * 64) return;
        int node = idx >> 6, c2 = idx & 63;
        int col = c2 * 2;
        float2 v = make_float2(0.f, 0.f);
        if (col < F_IN) v = *(const float2*)(X + (size_t)node * F_IN + col);
        int slice = col >> 5, within = col & 31;
        size_t dst = ((size_t)slice * N_NODES + node) * 16 + (within >> 1);
        ((__half2*)Xs)[dst] = __floats2half2_rn(v.x, v.y);
    } else if (b < PB_W1) {
        w_split_body(g1_w1, F_IN, F_IN, 128, w1h, w1l, (b - PB_XH) * 256 + t);
    } else if (b < PB_W2) {
        w_split_body(g1_w2, F_IN, F_IN, 128, w2h, w2l, (b - PB_W1) * 256 + t);
    } else if (b < PB_W4) {
        w_split_body(g2_w2, DIM, DIM, 32, w4h, w4l, (b - PB_W2) * 256 + t);
    } else {
        int i = (b - PB_W4) * 256 + t;
        if (i >= N_NODES) return;
        int cur = batch[i];
        int prev = (i == 0) ? -1 : batch[i - 1];
        for (int g = prev + 1; g <= cur; g++) goff[g] = i;
        if (i == N_NODES - 1) {
            for (int g = cur + 1; g <= N_GRAPHS; g++) goff[g] = N_NODES;
        }
    }
}

// ------- phase A: XCD-replicated bucket append (writes stay in local L2)
__global__ __launch_bounds__(256) void bucket_append(const int* __restrict__ src,
                                                     const int* __restrict__ dst,
                                                     int* __restrict__ bcur_pad,
                                                     int* __restrict__ bucket, int n) {
    unsigned xcc = 0;
    asm volatile("s_getreg_b32 %0, hwreg(HW_REG_XCC_ID)" : "=s"(xcc));
    int r = (int)(xcc & (NREP - 1));
    int i = blockIdx.x * 256 + threadIdx.x;
    if (i < n) {
        int d = dst[i];
        int b = d >> 5;
        size_t slot = (size_t)b * NREP + r;
        int c = atomicAdd(&bcur_pad[slot * PAD], 1);
        if (c < RCAP) bucket[slot * RCAP + c] = ((d & 31) << 16) | src[i];
    }
}

// ---------------- phase B: per-bucket LDS binning -> coalesced perm/deg write
__global__ __launch_bounds__(256) void bin_build(const int* __restrict__ bcur_pad,
                                                 const int* __restrict__ bucket,
                                                 int* __restrict__ perm_pad,
                                                 int* __restrict__ deg) {
    __shared__ int bins[32][CAP];
    __shared__ int lcur[32];
    int b = blockIdx.x, t = threadIdx.x;
    if (t < 32) lcur[t] = 0;
    __syncthreads();
    for (int r = 0; r < NREP; r++) {
        size_t slot = (size_t)b * NREP + r;
        int count = min(bcur_pad[slot * PAD], RCAP);
        for (int i = t; i < count; i += 256) {
            int e = bucket[slot * RCAP + i];
            int l = e >> 16, s = e & 0xFFFF;
            int c = atomicAdd(&lcur[l], 1);
            if (c < CAP) bins[l][c] = s;
        }
    }
    __syncthreads();
    if (t < 32) {
        int node = b * 32 + t;
        if (node < N_NODES) deg[node] = min(lcur[t], CAP);
    }
    for (int i = t; i < 32 * (CAP / 4); i += 256) {
        int l = i / (CAP / 4), q = i % (CAP / 4);
        int node = b * 32 + l;
        if (node < N_NODES) {
            ((int4*)&perm_pad[(size_t)node * CAP])[q] = ((const int4*)bins[l])[q];
        }
    }
}

// ---- layer-1 aggregation, feature-sliced: slice table (3.2 MB) is L2-resident.
// grid = (ceil(M/32), NSLICE); block = 4 waves x 8 nodes.
// wave: 4 edge-groups x 16 lanes (half2/lane = 64 B per edge-slice gather).
__global__ __launch_bounds__(256) void agg_slice(const float* __restrict__ X,
                                                 const __half* __restrict__ Xs,
                                                 const int* __restrict__ deg_arr,
                                                 const int* __restrict__ perm_pad,
                                                 float* __restrict__ out, int M) {
    int slice = blockIdx.y;
    int base = slice * 32;
    int wave = threadIdx.x >> 6;
    int lane = threadIdx.x & 63;
    int f = lane & 15, g = lane >> 4;
    bool fvalid = (base + 2 * f) < F_IN;      // slice 3: only f < 8
    const __half* tab = Xs + (size_t)slice * N_NODES * 32;
    int n0 = blockIdx.x * 32 + wave * 8;
    int n1 = min(n0 + 8, M);
    for (int n = n0; n < n1; n++) {
        int deg = deg_arr[n];
        const int* pl = perm_pad + (size_t)n * CAP;
        float ax = 0.f, ay = 0.f;
        int e = g;
        for (; e + 4 < deg; e += 8) {
            int s0 = pl[e], s1 = pl[e + 4];
            float2 v0 = __half22float2(*(const __half2*)(tab + (size_t)s0 * 32 + 2 * f));
            float2 v1 = __half22float2(*(const __half2*)(tab + (size_t)s1 * 32 + 2 * f));
            ax += v0.x + v1.x;
            ay += v0.y + v1.y;
        }
        if (e < deg) {
            int s0 = pl[e];
            float2 v0 = __half22float2(*(const __half2*)(tab + (size_t)s0 * 32 + 2 * f));
            ax += v0.x;
            ay += v0.y;
        }
        ax += __shfl_xor(ax, 16); ax += __shfl_xor(ax, 32);
        ay += __shfl_xor(ay, 16); ay += __shfl_xor(ay, 32);
        if (g == 0 && fvalid) {
            float2 self = *(const float2*)(X + (size_t)n * F_IN + base + 2 * f);
            *(float2*)(out + (size_t)n * F_IN + base + 2 * f) =
                make_float2(self.x + ax, self.y + ay);
        }
    }
}

// ---------- layer-2 aggregation on 32-wide fp16 y rows (quarter-wave/edge)
__global__ __launch_bounds__(256) void agg32_kernel(const __half* __restrict__ Y,
                                                    const int* __restrict__ deg_arr,
                                                    const int* __restrict__ perm_pad,
                                                    const float* __restrict__ c0,
                                                    const float* __restrict__ b1,
                                                    float* __restrict__ out, int M) {
    int w = (blockIdx.x * 256 + threadIdx.x) >> 6;
    int lane = threadIdx.x & 63;
    if (w >= M) return;
    int f = lane & 15;
    int g = lane >> 4;
    int deg = deg_arr[w];
    const int* pl = perm_pad + (size_t)w * CAP;
    float ax = 0.f, ay = 0.f;
    int e = g;
    for (; e + 4 < deg; e += 8) {
        int s0 = pl[e], s1 = pl[e + 4];
        float2 v0 = __half22float2(*(const __half2*)(Y + (size_t)s0 * DIM + 2 * f));
        float2 v1 = __half22float2(*(const __half2*)(Y + (size_t)s1 * DIM + 2 * f));
        ax += v0.x + v1.x;
        ay += v0.y + v1.y;
    }
    if (e < deg) {
        int s0 = pl[e];
        float2 v0 = __half22float2(*(const __half2*)(Y + (size_t)s0 * DIM + 2 * f));
        ax += v0.x;
        ay += v0.y;
    }
    ax += __shfl_xor(ax, 16); ax += __shfl_xor(ax, 32);
    ay += __shfl_xor(ay, 16); ay += __shfl_xor(ay, 32);
    if (g == 0) {
        float2 self = __half22float2(*(const __half2*)(Y + (size_t)w * DIM + 2 * f));
        float deg1 = (float)(deg + 1);
        float zx = self.x + ax + deg1 * c0[2 * f] + b1[2 * f];
        float zy = self.y + ay + deg1 * c0[2 * f + 1] + b1[2 * f + 1];
        *(float2*)(out + (size_t)w * DIM + 2 * f) = make_float2(fmaxf(zx, 0.f), fmaxf(zy, 0.f));
    }
}

// ------- BN1-folded W3 split: W3'[k][n] = s1[k]*W3[k][n]; c0[n] = sum t1[k]W3[k][n]
__global__ __launch_bounds__(256) void w3_fold(const float* __restrict__ W,   // [112][32]
                                               const float* __restrict__ s1,
                                               const float* __restrict__ t1,
                                               unsigned short* __restrict__ hi_t,  // [32][128]
                                               unsigned short* __restrict__ lo_t,
                                               float* __restrict__ c0) {
    int idx = blockIdx.x * 256 + threadIdx.x;
    if (idx < DIM * 128) {
        int n = idx >> 7, k = idx & 127;
        float v = (k < F_IN) ? s1[k] * W[(size_t)k * DIM + n] : 0.f;
        unsigned short h = f2bf(v);
        hi_t[idx] = h;
        lo_t[idx] = f2bf(v - bf2f(h));
    }
    if (blockIdx.x == 0 && threadIdx.x < DIM) {
        int n = threadIdx.x;
        float acc = 0.f;
        for (int k = 0; k < F_IN; k++) acc += t1[k] * W[(size_t)k * DIM + n];
        c0[n] = acc;
    }
}

// ------------------------- split-bf16 MFMA GEMM: C = act(A @ W + bias)
template <int NT, int KC, int K, bool RELU, int CHS>
__global__ __launch_bounds__(256) void gemm_mfma(const float* __restrict__ A,
                                                 const unsigned short* __restrict__ Whi,
                                                 const unsigned short* __restrict__ Wlo,
                                                 const float* __restrict__ bias,
                                                 float* __restrict__ C,
                                                 __half* __restrict__ Ch, int M) {
    constexpr int N = NT * 16;
    constexpr int Kpad = KC * 32;
    __shared__ __align__(16) unsigned short Ah[64 * 32];
    __shared__ __align__(16) unsigned short Al[64 * 32];
    __shared__ __align__(16) unsigned short Wh[N * 32];
    __shared__ __align__(16) unsigned short Wl[N * 32];
    int t = threadIdx.x;
    int lane = t & 63, wid = t >> 6;
    int r0 = blockIdx.x * 64;
    int m = lane & 15, quad = lane >> 4;

    float4v acc[NT];
#pragma unroll
    for (int nt = 0; nt < NT; nt++) acc[nt] = (float4v){0.f, 0.f, 0.f, 0.f};

    for (int c = 0; c < KC; c++) {
        int kc = c * 32;
#pragma unroll
        for (int i = 0; i < 2; i++) {
            int idx = t + i * 256;
            int row = idx >> 3, c4 = idx & 7;
            int col = kc + c4 * 4;
            int grow = r0 + row;
            float4 v = make_float4(0.f, 0.f, 0.f, 0.f);
            if (grow < M) {
                if (col + 3 < K) {
                    v = *(const float4*)(A + (size_t)grow * K + col);
                } else {
                    float tmp[4] = {0.f, 0.f, 0.f, 0.f};
                    for (int j = 0; j < 4; j++) if (col + j < K) tmp[j] = A[(size_t)grow * K + col + j];
                    v = make_float4(tmp[0], tmp[1], tmp[2], tmp[3]);
                }
            }
            unsigned short h0 = f2bf(v.x), h1 = f2bf(v.y), h2 = f2bf(v.z), h3 = f2bf(v.w);
            unsigned short l0 = f2bf(v.x - bf2f(h0)), l1 = f2bf(v.y - bf2f(h1));
            unsigned short l2 = f2bf(v.z - bf2f(h2)), l3 = f2bf(v.w - bf2f(h3));
            int o = row * 32 + c4 * 4;
            *(uint2*)&Ah[o] = make_uint2((unsigned)h0 | ((unsigned)h1 << 16), (unsigned)h2 | ((unsigned)h3 << 16));
            *(uint2*)&Al[o] = make_uint2((unsigned)l0 | ((unsigned)l1 << 16), (unsigned)l2 | ((unsigned)l3 << 16));
        }
        for (int idx = t; idx < N * 8; idx += 256) {
            int n = idx >> 3, w = idx & 7;
            int gsrc = n * (Kpad / 4) + (kc >> 2) + w;
            ((uint2*)Wh)[idx] = ((const uint2*)Whi)[gsrc];
            ((uint2*)Wl)[idx] = ((const uint2*)Wlo)[gsrc];
        }
        __syncthreads();
        short8 a_h = *(const short8*)&Ah[(wid * 16 + m) * 32 + quad * 8];
        short8 a_l = *(const short8*)&Al[(wid * 16 + m) * 32 + quad * 8];
#pragma unroll
        for (int nt = 0; nt < NT; nt++) {
            short8 b_h = *(const short8*)&Wh[(nt * 16 + m) * 32 + quad * 8];
            short8 b_l = *(const short8*)&Wl[(nt * 16 + m) * 32 + quad * 8];
            acc[nt] = __builtin_amdgcn_mfma_f32_16x16x32_bf16(a_h, b_h, acc[nt], 0, 0, 0);
            acc[nt] = __builtin_amdgcn_mfma_f32_16x16x32_bf16(a_h, b_l, acc[nt], 0, 0, 0);
            acc[nt] = __builtin_amdgcn_mfma_f32_16x16x32_bf16(a_l, b_h, acc[nt], 0, 0, 0);
        }
        __syncthreads();
    }
#pragma unroll
    for (int nt = 0; nt < NT; nt++) {
        int col = nt * 16 + m;
        float b = bias ? bias[col] : 0.f;
#pragma unroll
        for (int r = 0; r < 4; r++) {
            int row = r0 + wid * 16 + quad * 4 + r;
            if (row < M) {
                float v = acc[nt][r] + b;
                if (RELU) v = fmaxf(v, 0.f);
                if (C) C[(size_t)row * N + col] = v;
                if (Ch) Ch[(size_t)row * CHS + col] = __float2half(v);
            }
        }
    }
}

// ----------------------------------- BN stats: register acc -> block partials
template <int F, int BLOCKS>
__global__ __launch_bounds__(256) void bn_stats_pairs(const float* __restrict__ H, int M,
                                                      float* __restrict__ pbuf) {
    constexpr int P = F / 2;
    __shared__ float ls[4][2 * F];
    int t = threadIdx.x, lane = t & 63, wv = t >> 6;
    bool act = lane < P;
    float sx = 0.f, sy = 0.f, qx = 0.f, qy = 0.f;
    for (int r = blockIdx.x * 4 + wv; r < M; r += BLOCKS * 4) {
        if (act) {
            float2 v = *(const float2*)(H + (size_t)r * F + 2 * lane);
            sx += v.x; sy += v.y; qx += v.x * v.x; qy += v.y * v.y;
        }
    }
    if (act) {
        ls[wv][2 * lane] = sx; ls[wv][2 * lane + 1] = sy;
        ls[wv][F + 2 * lane] = qx; ls[wv][F + 2 * lane + 1] = qy;
    }
    __syncthreads();
    for (int j = t; j < 2 * F; j += 256) {
        pbuf[(size_t)blockIdx.x * 2 * F + j] = ls[0][j] + ls[1][j] + ls[2][j] + ls[3][j];
    }
}

template <int BLOCKS>
__global__ __launch_bounds__(256) void bn_stats32(const float* __restrict__ H, int M,
                                                  float* __restrict__ pbuf) {
    __shared__ float ls[8][64];
    int t = threadIdx.x;
    int col = t & 31, rg = t >> 5;
    float s = 0.f, q = 0.f;
    for (int r = blockIdx.x * 8 + rg; r < M; r += BLOCKS * 8) {
        float v = H[(size_t)r * 32 + col];
        s += v; q += v * v;
    }
    ls[rg][col] = s;
    ls[rg][32 + col] = q;
    __syncthreads();
    if (t < 64) {
        float a = 0.f;
        for (int i = 0; i < 8; i++) a += ls[i][t];
        pbuf[(size_t)blockIdx.x * 64 + t] = a;
    }
}

template <int F, int BLOCKS>
__global__ __launch_bounds__(128) void bn_finalize(const float* __restrict__ pbuf, const float* __restrict__ g,
                                                   const float* __restrict__ b, float* __restrict__ s,
                                                   float* __restrict__ tt, int M) {
    int j = threadIdx.x;
    if (j < F) {
        double sum = 0.0, sq = 0.0;
        for (int i = 0; i < BLOCKS; i++) {
            sum += (double)pbuf[(size_t)i * 2 * F + j];
            sq  += (double)pbuf[(size_t)i * 2 * F + F + j];
        }
        double mean = sum / M;
        double var = sq / M - mean * mean;
        double sc = (double)g[j] / sqrt(var + BN_EPS);
        s[j] = (float)sc;
        tt[j] = (float)((double)b[j] - mean * sc);
    }
}

// -------------------------------------------- pool (BN2 folded) + head
__global__ __launch_bounds__(256) void pool_head(const float* __restrict__ H2, const int* __restrict__ goff,
                                                 const float* __restrict__ s2, const float* __restrict__ t2,
                                                 const float* __restrict__ fcxd_w, const float* __restrict__ fcxd_b,
                                                 const float* __restrict__ fc1_w, const float* __restrict__ fc1_b,
                                                 const float* __restrict__ fc2_w, const float* __restrict__ fc2_b,
                                                 const float* __restrict__ fc3_w, const float* __restrict__ fc3_b,
                                                 const float* __restrict__ fc4_w, const float* __restrict__ fc4_b,
                                                 const float* __restrict__ fc5_w, const float* __restrict__ fc5_b,
                                                 float* __restrict__ out) {
    __shared__ float red[256];
    __shared__ float p[64];
    __shared__ float z[64];
    int g = blockIdx.x, t = threadIdx.x;
    int r0 = goff[g], r1 = goff[g + 1];
    int cnt = r1 - r0;
    int j = t & 31, rr = t >> 5;
    float a = 0.f;
    for (int r = r0 + rr; r < r1; r += 8) a += H2[(size_t)r * DIM + j];
    red[t] = a;
    __syncthreads();
    if (t < 32) {
        float ssum = 0.f;
        for (int q = 0; q < 8; q++) ssum += red[q * 32 + j];
        p[j] = s2[j] * ssum + (float)cnt * t2[j];
    }
    __syncthreads();
    if (t < 64) {
        float acc = fcxd_b[t];
        for (int i = 0; i < 32; i++) acc += p[i] * fcxd_w[i * 64 + t];
        z[t] = fmaxf(acc, 0.f);
    }
    __syncthreads();
    if (t < 32) {
        float acc = fc1_b[t];
        for (int i = 0; i < 64; i++) acc += z[i] * fc1_w[i * 32 + t];
        p[t] = acc;
    }
    __syncthreads();
    if (t < 16) {
        float acc = fc2_b[t];
        for (int i = 0; i < 32; i++) acc += p[i] * fc2_w[i * 16 + t];
        z[t] = acc;
    }
    __syncthreads();
    if (t < 8) {
        float acc = fc3_b[t];
        for (int i = 0; i < 16; i++) acc += z[i] * fc3_w[i * 8 + t];
        p[t] = acc;
    }
    __syncthreads();
    if (t < 2) {
        float acc = fc4_b[t];
        for (int i = 0; i < 8; i++) acc += p[i] * fc4_w[i * 2 + t];
        z[t] = acc;
    }
    __syncthreads();
    if (t == 0) {
        out[g] = z[0] * fc5_w[0] + z[1] * fc5_w[1] + fc5_b[0];
    }
}

// ---------------------------------------------------------------- launch
extern "C" void kernel_launch(void* const* d_in, const int* in_sizes, int n_in,
                              void* d_out, int out_size, void* d_ws, size_t ws_size,
                              hipStream_t stream) {
    const float* x     = (const float*)d_in[0];
    const int*   src   = (const int*)d_in[1];
    const int*   dst   = (const int*)d_in[2];
    const int*   batch = (const int*)d_in[3];
    const float* g1_w1 = (const float*)d_in[4];
    const float* g1_b1 = (const float*)d_in[5];
    const float* g1_w2 = (const float*)d_in[6];
    const float* g1_b2 = (const float*)d_in[7];
    const float* bn1_g = (const float*)d_in[8];
    const float* bn1_b = (const float*)d_in[9];
    const float* g2_w1 = (const float*)d_in[10];
    const float* g2_b1 = (const float*)d_in[11];
    const float* g2_w2 = (const float*)d_in[12];
    const float* g2_b2 = (const float*)d_in[13];
    const float* bn2_g = (const float*)d_in[14];
    const float* bn2_b = (const float*)d_in[15];
    const float* fcxd_w = (const float*)d_in[16];
    const float* fcxd_b = (const float*)d_in[17];
    const float* fc1_w = (const float*)d_in[18];
    const float* fc1_b = (const float*)d_in[19];
    const float* fc2_w = (const float*)d_in[20];
    const float* fc2_b = (const float*)d_in[21];
    const float* fc3_w = (const float*)d_in[22];
    const float* fc3_b = (const float*)d_in[23];
    const float* fc4_w = (const float*)d_in[24];
    const float* fc4_b = (const float*)d_in[25];
    const float* fc5_w = (const float*)d_in[26];
    const float* fc5_b = (const float*)d_in[27];
    float* out = (float*)d_out;
    char* ws = (char*)d_ws;

    constexpr int BN1_BLOCKS = 256;
    constexpr int BN2_BLOCKS = 128;

    size_t off = 0;
    auto take = [&](size_t bytes) { size_t o = off; off += (bytes + 255) & ~(size_t)255; return o; };
    int* bcur_pad  = (int*)(ws + take((size_t)NB * NREP * PAD * 4));    // zeroed (1.6 MB)
    size_t zero_bytes = off;
    int* bucket    = (int*)(ws + take((size_t)NB * NREP * RCAP * 4));
    int* perm_pad  = (int*)(ws + take((size_t)N_NODES * CAP * 4));
    int* deg       = (int*)(ws + take((size_t)N_NODES * 4));
    int* goff      = (int*)(ws + take((size_t)(N_GRAPHS + 4) * 4));
    float* s1      = (float*)(ws + take(F_IN * 4));
    float* t1      = (float*)(ws + take(F_IN * 4));
    float* s2      = (float*)(ws + take(DIM * 4));
    float* t2      = (float*)(ws + take(DIM * 4));
    float* c0      = (float*)(ws + take(DIM * 4));
    float* pb1     = (float*)(ws + take((size_t)BN1_BLOCKS * 2 * F_IN * 4));
    float* pb2     = (float*)(ws + take((size_t)BN2_BLOCKS * 2 * DIM * 4));
    unsigned short* w1h = (unsigned short*)(ws + take((size_t)F_IN * 128 * 2));
    unsigned short* w1l = (unsigned short*)(ws + take((size_t)F_IN * 128 * 2));
    unsigned short* w2h = (unsigned short*)(ws + take((size_t)F_IN * 128 * 2));
    unsigned short* w2l = (unsigned short*)(ws + take((size_t)F_IN * 128 * 2));
    unsigned short* w3h = (unsigned short*)(ws + take((size_t)DIM * 128 * 2));
    unsigned short* w3l = (unsigned short*)(ws + take((size_t)DIM * 128 * 2));
    unsigned short* w4h = (unsigned short*)(ws + take((size_t)DIM * 32 * 2));
    unsigned short* w4l = (unsigned short*)(ws + take((size_t)DIM * 32 * 2));
    __half* xs     = (__half*)(ws + take((size_t)NSLICE * N_NODES * 32 * 2));
    __half* y_half = (__half*)(ws + take((size_t)N_NODES * DIM * 2));
    float* bufA    = (float*)(ws + take((size_t)N_NODES * F_IN * 4));
    float* bufB    = (float*)(ws + take((size_t)N_NODES * F_IN * 4));
    float* bufS1   = (float*)(ws + take((size_t)N_NODES * DIM * 4));
    float* bufS2   = (float*)(ws + take((size_t)N_NODES * DIM * 4));
    (void)ws_size; (void)in_sizes; (void)n_in; (void)out_size;

    hipMemsetAsync(ws, 0, zero_bytes, stream);

    // merged prep: x->fp16 slice-major, weight splits, graph bounds
    prep_kernel<<<PB_GB, 256, 0, stream>>>(x, xs,
                                           g1_w1, w1h, w1l, g1_w2, w2h, w2l, g2_w2, w4h, w4l,
                                           batch, goff);

    // graph build: XCD-replicated bucket append -> per-bucket LDS binning
    bucket_append<<<(N_EDGES + 255) / 256, 256, 0, stream>>>(src, dst, bcur_pad, bucket, N_EDGES);
    bin_build<<<NB, 256, 0, stream>>>(bcur_pad, bucket, perm_pad, deg);

    const int AGG_BLOCKS = (N_NODES + 3) / 4;
    const int GEMM_MB = (N_NODES + 63) / 64;

    // GIN layer 1 (feature-sliced gather: slice table L2-resident)
    agg_slice<<<dim3((N_NODES + 31) / 32, NSLICE), 256, 0, stream>>>(x, xs, deg, perm_pad, bufA, N_NODES);
    gemm_mfma<7, 4, F_IN, true, 0><<<GEMM_MB, 256, 0, stream>>>(bufA, w1h, w1l, g1_b1, bufB, nullptr, N_NODES);
    gemm_mfma<7, 4, F_IN, true, 0><<<GEMM_MB, 256, 0, stream>>>(bufB, w2h, w2l, g1_b2, bufA, nullptr, N_NODES);
    bn_stats_pairs<F_IN, BN1_BLOCKS><<<BN1_BLOCKS, 256, 0, stream>>>(bufA, N_NODES, pb1);
    bn_finalize<F_IN, BN1_BLOCKS><<<1, 128, 0, stream>>>(pb1, bn1_g, bn1_b, s1, t1, N_NODES);

    // GIN layer 2: linear-first (BN1 folded into W3' and c0), then 32-wide agg
    w3_fold<<<(DIM * 128 + 255) / 256, 256, 0, stream>>>(g2_w1, s1, t1, w3h, w3l, c0);
    gemm_mfma<2, 4, F_IN, false, DIM><<<GEMM_MB, 256, 0, stream>>>(bufA, w3h, w3l, nullptr, nullptr, y_half, N_NODES);
    agg32_kernel<<<AGG_BLOCKS, 256, 0, stream>>>(y_half, deg, perm_pad, c0, g2_b1, bufS1, N_NODES);
    gemm_mfma<2, 1, DIM, true, 0><<<GEMM_MB, 256, 0, stream>>>(bufS1, w4h, w4l, g2_b2, bufS2, nullptr, N_NODES);
    bn_stats32<BN2_BLOCKS><<<BN2_BLOCKS, 256, 0, stream>>>(bufS2, N_NODES, pb2);
    bn_finalize<DIM, BN2_BLOCKS><<<1, 64, 0, stream>>>(pb2, bn2_g, bn2_b, s2, t2, N_NODES);

    // pool (BN2 folded) + dense head
    pool_head<<<N_GRAPHS, 256, 0, stream>>>(bufS2, goff, s2, t2,
                                            fcxd_w, fcxd_b, fc1_w, fc1_b, fc2_w, fc2_b,
                                            fc3_w, fc3_b, fc4_w, fc4_b, fc5_w, fc5_b, out);
}

// Round 11
// 343.062 us; speedup vs baseline: 1.1490x; 1.1490x over previous
//
#include <hip/hip_runtime.h>
#include <hip/hip_fp16.h>

#define N_NODES 50000
#define N_EDGES 800000
#define N_GRAPHS 256
#define F_IN 112
#define DIM 32
#define BN_EPS 1e-5
#define PAD 32     // ints per atomic slot: one 128-B line per cursor
#define HROW 128   // fp16 gather-row stride (256 B = exactly 2 lines, zero waste)
#define CAP 64     // edge slots per node (P(deg>63) ~ 1e-19 for Poisson(16))
#define NB 1563    // buckets = ceil(50000/32)
#define NREP 8     // one bucket replica per XCD
#define RCAP 128   // entries per replica-bucket (Poisson(64), 8 sigma headroom)

typedef __attribute__((ext_vector_type(8))) short short8;
typedef __attribute__((ext_vector_type(4))) float float4v;

// ---- bf16 helpers (RNE) ----
__device__ inline unsigned short f2bf(float f) {
    union { float f; unsigned int u; } v; v.f = f;
    unsigned int u = v.u;
    u += 0x7FFFu + ((u >> 16) & 1u);
    return (unsigned short)(u >> 16);
}
__device__ inline float bf2f(unsigned short h) {
    union { unsigned int u; float f; } v; v.u = ((unsigned int)h) << 16;
    return v.f;
}

__device__ inline void w_split_body(const float* __restrict__ W, int K, int N, int Kpad,
                                    unsigned short* __restrict__ hi_t,
                                    unsigned short* __restrict__ lo_t, int idx) {
    if (idx >= N * Kpad) return;
    int n = idx / Kpad, k = idx - n * Kpad;
    float v = (k < K) ? W[(size_t)k * N + n] : 0.f;
    unsigned short h = f2bf(v);
    hi_t[idx] = h;
    lo_t[idx] = f2bf(v - bf2f(h));
}

// ------- merged prep: x -> padded fp16 rows, 3 weight splits, graph bounds
#define PB_XH 12500                 // 50000*64 half2 / 256
#define PB_W1 (PB_XH + 56)
#define PB_W2 (PB_W1 + 56)
#define PB_W4 (PB_W2 + 4)
#define PB_GB (PB_W4 + 196)        // total blocks
__global__ __launch_bounds__(256) void prep_kernel(const float* __restrict__ X, __half* __restrict__ Xh,
                                                   const float* __restrict__ g1_w1, unsigned short* w1h, unsigned short* w1l,
                                                   const float* __restrict__ g1_w2, unsigned short* w2h, unsigned short* w2l,
                                                   const float* __restrict__ g2_w2, unsigned short* w4h, unsigned short* w4l,
                                                   const int* __restrict__ batch, int* __restrict__ goff) {
    int b = blockIdx.x, t = threadIdx.x;
    if (b < PB_XH) {
        int idx = b * 256 + t;                       // one half2 per thread
        if (idx >= N_NODES * (HROW / 2)) return;
        int row = idx / (HROW / 2), c2 = idx - row * (HROW / 2);
        int col = c2 * 2;
        float2 v = make_float2(0.f, 0.f);
        if (col < F_IN) v = *(const float2*)(X + (size_t)row * F_IN + col);
        ((__half2*)Xh)[idx] = __floats2half2_rn(v.x, v.y);
    } else if (b < PB_W1) {
        w_split_body(g1_w1, F_IN, F_IN, 128, w1h, w1l, (b - PB_XH) * 256 + t);
    } else if (b < PB_W2) {
        w_split_body(g1_w2, F_IN, F_IN, 128, w2h, w2l, (b - PB_W1) * 256 + t);
    } else if (b < PB_W4) {
        w_split_body(g2_w2, DIM, DIM, 32, w4h, w4l, (b - PB_W2) * 256 + t);
    } else {
        int i = (b - PB_W4) * 256 + t;
        if (i >= N_NODES) return;
        int cur = batch[i];
        int prev = (i == 0) ? -1 : batch[i - 1];
        for (int g = prev + 1; g <= cur; g++) goff[g] = i;
        if (i == N_NODES - 1) {
            for (int g = cur + 1; g <= N_GRAPHS; g++) goff[g] = N_NODES;
        }
    }
}

// ------- phase A: XCD-replicated bucket append (writes stay in local L2)
__global__ __launch_bounds__(256) void bucket_append(const int* __restrict__ src,
                                                     const int* __restrict__ dst,
                                                     int* __restrict__ bcur_pad,
                                                     int* __restrict__ bucket, int n) {
    unsigned xcc = 0;
    asm volatile("s_getreg_b32 %0, hwreg(HW_REG_XCC_ID)" : "=s"(xcc));
    int r = (int)(xcc & (NREP - 1));
    int i = blockIdx.x * 256 + threadIdx.x;
    if (i < n) {
        int d = dst[i];
        int b = d >> 5;
        size_t slot = (size_t)b * NREP + r;
        int c = atomicAdd(&bcur_pad[slot * PAD], 1);
        if (c < RCAP) bucket[slot * RCAP + c] = ((d & 31) << 16) | src[i];
    }
}

// ---------------- phase B: per-bucket LDS binning -> coalesced perm/deg write
__global__ __launch_bounds__(256) void bin_build(const int* __restrict__ bcur_pad,
                                                 const int* __restrict__ bucket,
                                                 int* __restrict__ perm_pad,
                                                 int* __restrict__ deg) {
    __shared__ int bins[32][CAP];
    __shared__ int lcur[32];
    int b = blockIdx.x, t = threadIdx.x;
    if (t < 32) lcur[t] = 0;
    __syncthreads();
    for (int r = 0; r < NREP; r++) {
        size_t slot = (size_t)b * NREP + r;
        int count = min(bcur_pad[slot * PAD], RCAP);
        for (int i = t; i < count; i += 256) {
            int e = bucket[slot * RCAP + i];
            int l = e >> 16, s = e & 0xFFFF;
            int c = atomicAdd(&lcur[l], 1);
            if (c < CAP) bins[l][c] = s;
        }
    }
    __syncthreads();
    if (t < 32) {
        int node = b * 32 + t;
        if (node < N_NODES) deg[node] = min(lcur[t], CAP);
    }
    for (int i = t; i < 32 * (CAP / 4); i += 256) {
        int l = i / (CAP / 4), q = i % (CAP / 4);
        int node = b * 32 + l;
        if (node < N_NODES) {
            ((int4*)&perm_pad[(size_t)node * CAP])[q] = ((const int4*)bins[l])[q];
        }
    }
}

// ------------------- layer-1 aggregation (wave per node), fp16 gather
// All 64 lanes load (row zero-padded to 128 halves); 16 gathers in flight.
__global__ __launch_bounds__(256) void agg_kernel(const float* __restrict__ X,
                                                  const __half* __restrict__ Xh,
                                                  const int* __restrict__ deg_arr,
                                                  const int* __restrict__ perm_pad,
                                                  float* __restrict__ out, int M) {
    constexpr int P = F_IN / 2;
    int w = (blockIdx.x * 256 + threadIdx.x) >> 6;
    int lane = threadIdx.x & 63;
    if (w >= M) return;
    int deg = deg_arr[w];
    const int* pl = perm_pad + (size_t)w * CAP;
    float ax = 0.f, ay = 0.f;
    int e = 0;
    for (; e + 16 <= deg; e += 16) {
        int s[16];
#pragma unroll
        for (int j = 0; j < 16; j++) s[j] = pl[e + j];
        float2 v[16];
#pragma unroll
        for (int j = 0; j < 16; j++)
            v[j] = __half22float2(*(const __half2*)(Xh + (size_t)s[j] * HROW + 2 * lane));
#pragma unroll
        for (int j = 0; j < 16; j++) { ax += v[j].x; ay += v[j].y; }
    }
    for (; e + 4 <= deg; e += 4) {
        int s0 = pl[e], s1 = pl[e + 1], s2 = pl[e + 2], s3 = pl[e + 3];
        float2 v0 = __half22float2(*(const __half2*)(Xh + (size_t)s0 * HROW + 2 * lane));
        float2 v1 = __half22float2(*(const __half2*)(Xh + (size_t)s1 * HROW + 2 * lane));
        float2 v2 = __half22float2(*(const __half2*)(Xh + (size_t)s2 * HROW + 2 * lane));
        float2 v3 = __half22float2(*(const __half2*)(Xh + (size_t)s3 * HROW + 2 * lane));
        ax += (v0.x + v1.x) + (v2.x + v3.x);
        ay += (v0.y + v1.y) + (v2.y + v3.y);
    }
    for (; e < deg; e++) {
        int s = pl[e];
        float2 v = __half22float2(*(const __half2*)(Xh + (size_t)s * HROW + 2 * lane));
        ax += v.x;
        ay += v.y;
    }
    if (lane < P) {
        float2 self = *(const float2*)(X + (size_t)w * F_IN + 2 * lane);
        *(float2*)(out + (size_t)w * F_IN + 2 * lane) = make_float2(self.x + ax, self.y + ay);
    }
}

// ---------- layer-2 aggregation on 32-wide fp16 y rows (quarter-wave/edge)
__global__ __launch_bounds__(256) void agg32_kernel(const __half* __restrict__ Y,
                                                    const int* __restrict__ deg_arr,
                                                    const int* __restrict__ perm_pad,
                                                    const float* __restrict__ c0,
                                                    const float* __restrict__ b1,
                                                    float* __restrict__ out, int M) {
    int w = (blockIdx.x * 256 + threadIdx.x) >> 6;
    int lane = threadIdx.x & 63;
    if (w >= M) return;
    int f = lane & 15;
    int g = lane >> 4;
    int deg = deg_arr[w];
    const int* pl = perm_pad + (size_t)w * CAP;
    float ax = 0.f, ay = 0.f;
    int e = g;
    for (; e + 4 < deg; e += 8) {
        int s0 = pl[e], s1 = pl[e + 4];
        float2 v0 = __half22float2(*(const __half2*)(Y + (size_t)s0 * DIM + 2 * f));
        float2 v1 = __half22float2(*(const __half2*)(Y + (size_t)s1 * DIM + 2 * f));
        ax += v0.x + v1.x;
        ay += v0.y + v1.y;
    }
    if (e < deg) {
        int s0 = pl[e];
        float2 v0 = __half22float2(*(const __half2*)(Y + (size_t)s0 * DIM + 2 * f));
        ax += v0.x;
        ay += v0.y;
    }
    ax += __shfl_xor(ax, 16); ax += __shfl_xor(ax, 32);
    ay += __shfl_xor(ay, 16); ay += __shfl_xor(ay, 32);
    if (g == 0) {
        float2 self = __half22float2(*(const __half2*)(Y + (size_t)w * DIM + 2 * f));
        float deg1 = (float)(deg + 1);
        float zx = self.x + ax + deg1 * c0[2 * f] + b1[2 * f];
        float zy = self.y + ay + deg1 * c0[2 * f + 1] + b1[2 * f + 1];
        *(float2*)(out + (size_t)w * DIM + 2 * f) = make_float2(fmaxf(zx, 0.f), fmaxf(zy, 0.f));
    }
}

// ------- BN1-folded W3 split: W3'[k][n] = s1[k]*W3[k][n]; c0[n] = sum t1[k]W3[k][n]
__global__ __launch_bounds__(256) void w3_fold(const float* __restrict__ W,   // [112][32]
                                               const float* __restrict__ s1,
                                               const float* __restrict__ t1,
                                               unsigned short* __restrict__ hi_t,  // [32][128]
                                               unsigned short* __restrict__ lo_t,
                                               float* __restrict__ c0) {
    int idx = blockIdx.x * 256 + threadIdx.x;
    if (idx < DIM * 128) {
        int n = idx >> 7, k = idx & 127;
        float v = (k < F_IN) ? s1[k] * W[(size_t)k * DIM + n] : 0.f;
        unsigned short h = f2bf(v);
        hi_t[idx] = h;
        lo_t[idx] = f2bf(v - bf2f(h));
    }
    if (blockIdx.x == 0 && threadIdx.x < DIM) {
        int n = threadIdx.x;
        float acc = 0.f;
        for (int k = 0; k < F_IN; k++) acc += t1[k] * W[(size_t)k * DIM + n];
        c0[n] = acc;
    }
}

// ------------------------- split-bf16 MFMA GEMM: C = act(A @ W + bias)
template <int NT, int KC, int K, bool RELU, int CHS>
__global__ __launch_bounds__(256) void gemm_mfma(const float* __restrict__ A,
                                                 const unsigned short* __restrict__ Whi,
                                                 const unsigned short* __restrict__ Wlo,
                                                 const float* __restrict__ bias,
                                                 float* __restrict__ C,
                                                 __half* __restrict__ Ch, int M) {
    constexpr int N = NT * 16;
    constexpr int Kpad = KC * 32;
    __shared__ __align__(16) unsigned short Ah[64 * 32];
    __shared__ __align__(16) unsigned short Al[64 * 32];
    __shared__ __align__(16) unsigned short Wh[N * 32];
    __shared__ __align__(16) unsigned short Wl[N * 32];
    int t = threadIdx.x;
    int lane = t & 63, wid = t >> 6;
    int r0 = blockIdx.x * 64;
    int m = lane & 15, quad = lane >> 4;

    float4v acc[NT];
#pragma unroll
    for (int nt = 0; nt < NT; nt++) acc[nt] = (float4v){0.f, 0.f, 0.f, 0.f};

    for (int c = 0; c < KC; c++) {
        int kc = c * 32;
#pragma unroll
        for (int i = 0; i < 2; i++) {
            int idx = t + i * 256;
            int row = idx >> 3, c4 = idx & 7;
            int col = kc + c4 * 4;
            int grow = r0 + row;
            float4 v = make_float4(0.f, 0.f, 0.f, 0.f);
            if (grow < M) {
                if (col + 3 < K) {
                    v = *(const float4*)(A + (size_t)grow * K + col);
                } else {
                    float tmp[4] = {0.f, 0.f, 0.f, 0.f};
                    for (int j = 0; j < 4; j++) if (col + j < K) tmp[j] = A[(size_t)grow * K + col + j];
                    v = make_float4(tmp[0], tmp[1], tmp[2], tmp[3]);
                }
            }
            unsigned short h0 = f2bf(v.x), h1 = f2bf(v.y), h2 = f2bf(v.z), h3 = f2bf(v.w);
            unsigned short l0 = f2bf(v.x - bf2f(h0)), l1 = f2bf(v.y - bf2f(h1));
            unsigned short l2 = f2bf(v.z - bf2f(h2)), l3 = f2bf(v.w - bf2f(h3));
            int o = row * 32 + c4 * 4;
            *(uint2*)&Ah[o] = make_uint2((unsigned)h0 | ((unsigned)h1 << 16), (unsigned)h2 | ((unsigned)h3 << 16));
            *(uint2*)&Al[o] = make_uint2((unsigned)l0 | ((unsigned)l1 << 16), (unsigned)l2 | ((unsigned)l3 << 16));
        }
        for (int idx = t; idx < N * 8; idx += 256) {
            int n = idx >> 3, w = idx & 7;
            int gsrc = n * (Kpad / 4) + (kc >> 2) + w;
            ((uint2*)Wh)[idx] = ((const uint2*)Whi)[gsrc];
            ((uint2*)Wl)[idx] = ((const uint2*)Wlo)[gsrc];
        }
        __syncthreads();
        short8 a_h = *(const short8*)&Ah[(wid * 16 + m) * 32 + quad * 8];
        short8 a_l = *(const short8*)&Al[(wid * 16 + m) * 32 + quad * 8];
#pragma unroll
        for (int nt = 0; nt < NT; nt++) {
            short8 b_h = *(const short8*)&Wh[(nt * 16 + m) * 32 + quad * 8];
            short8 b_l = *(const short8*)&Wl[(nt * 16 + m) * 32 + quad * 8];
            acc[nt] = __builtin_amdgcn_mfma_f32_16x16x32_bf16(a_h, b_h, acc[nt], 0, 0, 0);
            acc[nt] = __builtin_amdgcn_mfma_f32_16x16x32_bf16(a_h, b_l, acc[nt], 0, 0, 0);
            acc[nt] = __builtin_amdgcn_mfma_f32_16x16x32_bf16(a_l, b_h, acc[nt], 0, 0, 0);
        }
        __syncthreads();
    }
#pragma unroll
    for (int nt = 0; nt < NT; nt++) {
        int col = nt * 16 + m;
        float b = bias ? bias[col] : 0.f;
#pragma unroll
        for (int r = 0; r < 4; r++) {
            int row = r0 + wid * 16 + quad * 4 + r;
            if (row < M) {
                float v = acc[nt][r] + b;
                if (RELU) v = fmaxf(v, 0.f);
                if (C) C[(size_t)row * N + col] = v;
                if (Ch) Ch[(size_t)row * CHS + col] = __float2half(v);
            }
        }
    }
}

// ----------------------------------- BN stats: register acc -> block partials
template <int F, int BLOCKS>
__global__ __launch_bounds__(256) void bn_stats_pairs(const float* __restrict__ H, int M,
                                                      float* __restrict__ pbuf) {
    constexpr int P = F / 2;
    __shared__ float ls[4][2 * F];
    int t = threadIdx.x, lane = t & 63, wv = t >> 6;
    bool act = lane < P;
    float sx = 0.f, sy = 0.f, qx = 0.f, qy = 0.f;
    for (int r = blockIdx.x * 4 + wv; r < M; r += BLOCKS * 4) {
        if (act) {
            float2 v = *(const float2*)(H + (size_t)r * F + 2 * lane);
            sx += v.x; sy += v.y; qx += v.x * v.x; qy += v.y * v.y;
        }
    }
    if (act) {
        ls[wv][2 * lane] = sx; ls[wv][2 * lane + 1] = sy;
        ls[wv][F + 2 * lane] = qx; ls[wv][F + 2 * lane + 1] = qy;
    }
    __syncthreads();
    for (int j = t; j < 2 * F; j += 256) {
        pbuf[(size_t)blockIdx.x * 2 * F + j] = ls[0][j] + ls[1][j] + ls[2][j] + ls[3][j];
    }
}

template <int BLOCKS>
__global__ __launch_bounds__(256) void bn_stats32(const float* __restrict__ H, int M,
                                                  float* __restrict__ pbuf) {
    __shared__ float ls[8][64];
    int t = threadIdx.x;
    int col = t & 31, rg = t >> 5;
    float s = 0.f, q = 0.f;
    for (int r = blockIdx.x * 8 + rg; r < M; r += BLOCKS * 8) {
        float v = H[(size_t)r * 32 + col];
        s += v; q += v * v;
    }
    ls[rg][col] = s;
    ls[rg][32 + col] = q;
    __syncthreads();
    if (t < 64) {
        float a = 0.f;
        for (int i = 0; i < 8; i++) a += ls[i][t];
        pbuf[(size_t)blockIdx.x * 64 + t] = a;
    }
}

template <int F, int BLOCKS>
__global__ __launch_bounds__(128) void bn_finalize(const float* __restrict__ pbuf, const float* __restrict__ g,
                                                   const float* __restrict__ b, float* __restrict__ s,
                                                   float* __restrict__ tt, int M) {
    int j = threadIdx.x;
    if (j < F) {
        double sum = 0.0, sq = 0.0;
        for (int i = 0; i < BLOCKS; i++) {
            sum += (double)pbuf[(size_t)i * 2 * F + j];
            sq  += (double)pbuf[(size_t)i * 2 * F + F + j];
        }
        double mean = sum / M;
        double var = sq / M - mean * mean;
        double sc = (double)g[j] / sqrt(var + BN_EPS);
        s[j] = (float)sc;
        tt[j] = (float)((double)b[j] - mean * sc);
    }
}

// -------------------------------------------- pool (BN2 folded) + head
__global__ __launch_bounds__(256) void pool_head(const float* __restrict__ H2, const int* __restrict__ goff,
                                                 const float* __restrict__ s2, const float* __restrict__ t2,
                                                 const float* __restrict__ fcxd_w, const float* __restrict__ fcxd_b,
                                                 const float* __restrict__ fc1_w, const float* __restrict__ fc1_b,
                                                 const float* __restrict__ fc2_w, const float* __restrict__ fc2_b,
                                                 const float* __restrict__ fc3_w, const float* __restrict__ fc3_b,
                                                 const float* __restrict__ fc4_w, const float* __restrict__ fc4_b,
                                                 const float* __restrict__ fc5_w, const float* __restrict__ fc5_b,
                                                 float* __restrict__ out) {
    __shared__ float red[256];
    __shared__ float p[64];
    __shared__ float z[64];
    int g = blockIdx.x, t = threadIdx.x;
    int r0 = goff[g], r1 = goff[g + 1];
    int cnt = r1 - r0;
    int j = t & 31, rr = t >> 5;
    float a = 0.f;
    for (int r = r0 + rr; r < r1; r += 8) a += H2[(size_t)r * DIM + j];
    red[t] = a;
    __syncthreads();
    if (t < 32) {
        float ssum = 0.f;
        for (int q = 0; q < 8; q++) ssum += red[q * 32 + j];
        p[j] = s2[j] * ssum + (float)cnt * t2[j];
    }
    __syncthreads();
    if (t < 64) {
        float acc = fcxd_b[t];
        for (int i = 0; i < 32; i++) acc += p[i] * fcxd_w[i * 64 + t];
        z[t] = fmaxf(acc, 0.f);
    }
    __syncthreads();
    if (t < 32) {
        float acc = fc1_b[t];
        for (int i = 0; i < 64; i++) acc += z[i] * fc1_w[i * 32 + t];
        p[t] = acc;
    }
    __syncthreads();
    if (t < 16) {
        float acc = fc2_b[t];
        for (int i = 0; i < 32; i++) acc += p[i] * fc2_w[i * 16 + t];
        z[t] = acc;
    }
    __syncthreads();
    if (t < 8) {
        float acc = fc3_b[t];
        for (int i = 0; i < 16; i++) acc += z[i] * fc3_w[i * 8 + t];
        p[t] = acc;
    }
    __syncthreads();
    if (t < 2) {
        float acc = fc4_b[t];
        for (int i = 0; i < 8; i++) acc += p[i] * fc4_w[i * 2 + t];
        z[t] = acc;
    }
    __syncthreads();
    if (t == 0) {
        out[g] = z[0] * fc5_w[0] + z[1] * fc5_w[1] + fc5_b[0];
    }
}

// ---------------------------------------------------------------- launch
extern "C" void kernel_launch(void* const* d_in, const int* in_sizes, int n_in,
                              void* d_out, int out_size, void* d_ws, size_t ws_size,
                              hipStream_t stream) {
    const float* x     = (const float*)d_in[0];
    const int*   src   = (const int*)d_in[1];
    const int*   dst   = (const int*)d_in[2];
    const int*   batch = (const int*)d_in[3];
    const float* g1_w1 = (const float*)d_in[4];
    const float* g1_b1 = (const float*)d_in[5];
    const float* g1_w2 = (const float*)d_in[6];
    const float* g1_b2 = (const float*)d_in[7];
    const float* bn1_g = (const float*)d_in[8];
    const float* bn1_b = (const float*)d_in[9];
    const float* g2_w1 = (const float*)d_in[10];
    const float* g2_b1 = (const float*)d_in[11];
    const float* g2_w2 = (const float*)d_in[12];
    const float* g2_b2 = (const float*)d_in[13];
    const float* bn2_g = (const float*)d_in[14];
    const float* bn2_b = (const float*)d_in[15];
    const float* fcxd_w = (const float*)d_in[16];
    const float* fcxd_b = (const float*)d_in[17];
    const float* fc1_w = (const float*)d_in[18];
    const float* fc1_b = (const float*)d_in[19];
    const float* fc2_w = (const float*)d_in[20];
    const float* fc2_b = (const float*)d_in[21];
    const float* fc3_w = (const float*)d_in[22];
    const float* fc3_b = (const float*)d_in[23];
    const float* fc4_w = (const float*)d_in[24];
    const float* fc4_b = (const float*)d_in[25];
    const float* fc5_w = (const float*)d_in[26];
    const float* fc5_b = (const float*)d_in[27];
    float* out = (float*)d_out;
    char* ws = (char*)d_ws;

    constexpr int BN1_BLOCKS = 256;
    constexpr int BN2_BLOCKS = 128;

    size_t off = 0;
    auto take = [&](size_t bytes) { size_t o = off; off += (bytes + 255) & ~(size_t)255; return o; };
    int* bcur_pad  = (int*)(ws + take((size_t)NB * NREP * PAD * 4));    // zeroed (1.6 MB)
    size_t zero_bytes = off;
    int* bucket    = (int*)(ws + take((size_t)NB * NREP * RCAP * 4));
    int* perm_pad  = (int*)(ws + take((size_t)N_NODES * CAP * 4));
    int* deg       = (int*)(ws + take((size_t)N_NODES * 4));
    int* goff      = (int*)(ws + take((size_t)(N_GRAPHS + 4) * 4));
    float* s1      = (float*)(ws + take(F_IN * 4));
    float* t1      = (float*)(ws + take(F_IN * 4));
    float* s2      = (float*)(ws + take(DIM * 4));
    float* t2      = (float*)(ws + take(DIM * 4));
    float* c0      = (float*)(ws + take(DIM * 4));
    float* pb1     = (float*)(ws + take((size_t)BN1_BLOCKS * 2 * F_IN * 4));
    float* pb2     = (float*)(ws + take((size_t)BN2_BLOCKS * 2 * DIM * 4));
    unsigned short* w1h = (unsigned short*)(ws + take((size_t)F_IN * 128 * 2));
    unsigned short* w1l = (unsigned short*)(ws + take((size_t)F_IN * 128 * 2));
    unsigned short* w2h = (unsigned short*)(ws + take((size_t)F_IN * 128 * 2));
    unsigned short* w2l = (unsigned short*)(ws + take((size_t)F_IN * 128 * 2));
    unsigned short* w3h = (unsigned short*)(ws + take((size_t)DIM * 128 * 2));
    unsigned short* w3l = (unsigned short*)(ws + take((size_t)DIM * 128 * 2));
    unsigned short* w4h = (unsigned short*)(ws + take((size_t)DIM * 32 * 2));
    unsigned short* w4l = (unsigned short*)(ws + take((size_t)DIM * 32 * 2));
    __half* x_half = (__half*)(ws + take((size_t)N_NODES * HROW * 2));
    __half* y_half = (__half*)(ws + take((size_t)N_NODES * DIM * 2));
    float* bufA    = (float*)(ws + take((size_t)N_NODES * F_IN * 4));
    float* bufB    = (float*)(ws + take((size_t)N_NODES * F_IN * 4));
    float* bufS1   = (float*)(ws + take((size_t)N_NODES * DIM * 4));
    float* bufS2   = (float*)(ws + take((size_t)N_NODES * DIM * 4));
    (void)ws_size; (void)in_sizes; (void)n_in; (void)out_size;

    hipMemsetAsync(ws, 0, zero_bytes, stream);

    // merged prep: x->fp16 padded rows, weight splits, graph bounds
    prep_kernel<<<PB_GB, 256, 0, stream>>>(x, x_half,
                                           g1_w1, w1h, w1l, g1_w2, w2h, w2l, g2_w2, w4h, w4l,
                                           batch, goff);

    // graph build: XCD-replicated bucket append -> per-bucket LDS binning
    bucket_append<<<(N_EDGES + 255) / 256, 256, 0, stream>>>(src, dst, bcur_pad, bucket, N_EDGES);
    bin_build<<<NB, 256, 0, stream>>>(bcur_pad, bucket, perm_pad, deg);

    const int AGG_BLOCKS = (N_NODES + 3) / 4;
    const int GEMM_MB = (N_NODES + 63) / 64;

    // GIN layer 1
    agg_kernel<<<AGG_BLOCKS, 256, 0, stream>>>(x, x_half, deg, perm_pad, bufA, N_NODES);
    gemm_mfma<7, 4, F_IN, true, 0><<<GEMM_MB, 256, 0, stream>>>(bufA, w1h, w1l, g1_b1, bufB, nullptr, N_NODES);
    gemm_mfma<7, 4, F_IN, true, 0><<<GEMM_MB, 256, 0, stream>>>(bufB, w2h, w2l, g1_b2, bufA, nullptr, N_NODES);
    bn_stats_pairs<F_IN, BN1_BLOCKS><<<BN1_BLOCKS, 256, 0, stream>>>(bufA, N_NODES, pb1);
    bn_finalize<F_IN, BN1_BLOCKS><<<1, 128, 0, stream>>>(pb1, bn1_g, bn1_b, s1, t1, N_NODES);

    // GIN layer 2: linear-first (BN1 folded into W3' and c0), then 32-wide agg
    w3_fold<<<(DIM * 128 + 255) / 256, 256, 0, stream>>>(g2_w1, s1, t1, w3h, w3l, c0);
    gemm_mfma<2, 4, F_IN, false, DIM><<<GEMM_MB, 256, 0, stream>>>(bufA, w3h, w3l, nullptr, nullptr, y_half, N_NODES);
    agg32_kernel<<<AGG_BLOCKS, 256, 0, stream>>>(y_half, deg, perm_pad, c0, g2_b1, bufS1, N_NODES);
    gemm_mfma<2, 1, DIM, true, 0><<<GEMM_MB, 256, 0, stream>>>(bufS1, w4h, w4l, g2_b2, bufS2, nullptr, N_NODES);
    bn_stats32<BN2_BLOCKS><<<BN2_BLOCKS, 256, 0, stream>>>(bufS2, N_NODES, pb2);
    bn_finalize<DIM, BN2_BLOCKS><<<1, 64, 0, stream>>>(pb2, bn2_g, bn2_b, s2, t2, N_NODES);

    // pool (BN2 folded) + dense head
    pool_head<<<N_GRAPHS, 256, 0, stream>>>(bufS2, goff, s2, t2,
                                            fcxd_w, fcxd_b, fc1_w, fc1_b, fc2_w, fc2_b,
                                            fc3_w, fc3_b, fc4_w, fc4_b, fc5_w, fc5_b, out);
}